// Round 9
// baseline (207.997 us; speedup 1.0000x reference)
//
#include <hip/hip_runtime.h>

#define D 128
#define LN_EPS 1e-5f
#define WSTR 136    // Wt LDS row stride in shorts (272B = 17x16B: aligned, bank-min)

typedef __attribute__((ext_vector_type(8))) short short8;
typedef __attribute__((ext_vector_type(4))) float f32x4;

static __device__ __forceinline__ unsigned short f2bf(float f) {
    union { float f; unsigned u; } v; v.f = f;
    unsigned r = v.u + 0x7fffu + ((v.u >> 16) & 1u);   // RTNE
    return (unsigned short)(r >> 16);
}
static __device__ __forceinline__ unsigned pack2(float a, float b) {
    return (unsigned)f2bf(a) | ((unsigned)f2bf(b) << 16);
}
static __device__ __forceinline__ float bf2f(unsigned short u) {
    union { unsigned u; float f; } v; v.u = ((unsigned)u) << 16; return v.f;
}

// ---------------------------------------------------------------------------
// W prep: Wt = diag(g)W bf16 [out][in], c1 = g^T W, c2 = beta^T W + bias;
// Wpt = bf16 Wp^T.
// ---------------------------------------------------------------------------
__global__ __launch_bounds__(64)
void wprep_kernel(const float* __restrict__ Wq, const float* __restrict__ Wk,
                  const float* __restrict__ Wv, const float* __restrict__ Wp,
                  const float* __restrict__ gq, const float* __restrict__ betaq,
                  const float* __restrict__ biasq,
                  const float* __restrict__ gk, const float* __restrict__ betak,
                  const float* __restrict__ biask,
                  const float* __restrict__ gv, const float* __restrict__ betav,
                  const float* __restrict__ biasv,
                  unsigned* __restrict__ Wt, unsigned* __restrict__ Wpt,
                  float* __restrict__ c1, float* __restrict__ c2)
{
    const int id = blockIdx.x;
    const int w  = id >> 7;
    const int o  = id & 127;
    const int t  = threadIdx.x;
    if (w < 3) {
        const float* W  = (w == 0) ? Wq : (w == 1) ? Wk : Wv;
        const float* gg = (w == 0) ? gq : (w == 1) ? gk : gv;
        const float* bb = (w == 0) ? betaq : (w == 1) ? betak : betav;
        const float* bi = (w == 0) ? biasq : (w == 1) ? biask : biasv;
        const float w0 = W[(2 * t) * 128 + o];
        const float w1 = W[(2 * t + 1) * 128 + o];
        const float g0 = gg[2 * t], g1 = gg[2 * t + 1];
        const float b0 = bb[2 * t], b1 = bb[2 * t + 1];
        Wt[((size_t)w * 128 + o) * 64 + t] = pack2(g0 * w0, g1 * w1);
        float s1 = g0 * w0 + g1 * w1;
        float s2 = b0 * w0 + b1 * w1;
        #pragma unroll
        for (int off = 32; off > 0; off >>= 1) {
            s1 += __shfl_down(s1, off, 64);
            s2 += __shfl_down(s2, off, 64);
        }
        if (t == 0) { c1[w * 128 + o] = s1; c2[w * 128 + o] = s2 + bi[o]; }
    } else {
        Wpt[(size_t)o * 64 + t] = pack2(Wp[(2 * t) * 128 + o], Wp[(2 * t + 1) * 128 + o]);
    }
}

// ---------------------------------------------------------------------------
// LN+Linear body (64 rows per call). Wt staged in LDS by caller (read-only
// here). Stats via X·1 and diag(X·X^T) MFMAs, broadcast to all lanes via
// register shuffles (no LDS, no barrier — R7's predicated-LDS hazard is
// structurally gone).
// MODE 0: bf16 row-major. MODE 1: +scale (q). MODE 2: V^T scatter.
// ---------------------------------------------------------------------------
template<int PERL, int W1W2, int W2D, int MODE>
static __device__ __forceinline__
void ln_body(const float* __restrict__ in,
             const unsigned short* __restrict__ wlds,   // LDS, [128][WSTR]
             const float* __restrict__ c1, const float* __restrict__ c2,
             unsigned short* __restrict__ out,
             float scale, int rowbase, int t)
{
    const int wv   = t >> 6;
    const int lane = t & 63;
    const int m16  = lane & 15;
    const int g    = lane >> 4;
    const int row  = rowbase + wv * 16 + m16;

    const int l   = row / PERL, j = row - l * PERL;
    const int n   = j / W1W2, rem = j - n * W1W2;
    const int w1  = rem / W2D, w2 = rem - w1 * W2D;
    const int X   = l >> 3, Y = l & 7;
    const float* xrow = in + ((size_t)(((n * 8 + X) * 8 + Y) * 8 + w1) * W2D + w2) * D;

    short8 xf[4];
    #pragma unroll
    for (int kt = 0; kt < 4; ++kt) {
        const float4 a = *(const float4*)(xrow + kt * 32 + g * 8);
        const float4 b = *(const float4*)(xrow + kt * 32 + g * 8 + 4);
        short8 vv;
        vv[0] = (short)f2bf(a.x); vv[1] = (short)f2bf(a.y);
        vv[2] = (short)f2bf(a.z); vv[3] = (short)f2bf(a.w);
        vv[4] = (short)f2bf(b.x); vv[5] = (short)f2bf(b.y);
        vv[6] = (short)f2bf(b.z); vv[7] = (short)f2bf(b.w);
        xf[kt] = vv;
    }

    short8 ones;
    #pragma unroll
    for (int jj = 0; jj < 8; ++jj) ones[jj] = (short)0x3F80;
    f32x4 sums = {0.f, 0.f, 0.f, 0.f}, gram = {0.f, 0.f, 0.f, 0.f};
    #pragma unroll
    for (int kt = 0; kt < 4; ++kt) {
        sums = __builtin_amdgcn_mfma_f32_16x16x32_bf16(xf[kt], ones, sums, 0, 0, 0);
        gram = __builtin_amdgcn_mfma_f32_16x16x32_bf16(xf[kt], xf[kt], gram, 0, 0, 0);
    }
    // broadcast rowsum(m16) and diag-sumsq(m16) via shuffles.
    // source lane: g_s = m16>>2 (holds rows 4*g_s..+3), col = m16 (diag for gram).
    const int su = ((m16 >> 2) << 4) | m16;
    const float s0 = __shfl(sums[0], su, 64), s1 = __shfl(sums[1], su, 64);
    const float s2 = __shfl(sums[2], su, 64), s3 = __shfl(sums[3], su, 64);
    const float q0 = __shfl(gram[0], su, 64), q1 = __shfl(gram[1], su, 64);
    const float q2 = __shfl(gram[2], su, 64), q3 = __shfl(gram[3], su, 64);
    const int rr = m16 & 3;
    const float rs = (rr == 0) ? s0 : (rr == 1) ? s1 : (rr == 2) ? s2 : s3;
    const float rq = (rr == 0) ? q0 : (rr == 1) ? q1 : (rr == 2) ? q2 : q3;

    const float mu   = rs * (1.0f / 128.0f);
    const float msq  = rq * (1.0f / 128.0f);
    const float rstd = rsqrtf(msq - mu * mu + LN_EPS);
    const float rmu  = rstd * mu;

    f32x4 acc[8] = {{0,0,0,0},{0,0,0,0},{0,0,0,0},{0,0,0,0},
                    {0,0,0,0},{0,0,0,0},{0,0,0,0},{0,0,0,0}};
    #pragma unroll
    for (int kt = 0; kt < 4; ++kt) {
        #pragma unroll
        for (int ot = 0; ot < 8; ++ot) {
            const short8 aw = *(const short8*)&wlds[
                (ot * 16 + m16) * WSTR + kt * 32 + g * 8];
            acc[ot] = __builtin_amdgcn_mfma_f32_16x16x32_bf16(aw, xf[kt], acc[ot], 0, 0, 0);
        }
    }

    #pragma unroll
    for (int ot = 0; ot < 8; ++ot) {
        const int ob = ot * 16 + g * 4;
        const float4 cc1 = *(const float4*)&c1[ob];
        const float4 cc2 = *(const float4*)&c2[ob];
        float v0 = rstd * acc[ot][0] - rmu * cc1.x + cc2.x;
        float v1 = rstd * acc[ot][1] - rmu * cc1.y + cc2.y;
        float v2 = rstd * acc[ot][2] - rmu * cc1.z + cc2.z;
        float v3 = rstd * acc[ot][3] - rmu * cc1.w + cc2.w;
        if (MODE == 1) { v0 *= scale; v1 *= scale; v2 *= scale; v3 *= scale; }
        if (MODE == 2) {
            // transposed scatter: vtb[((l*4 + d>>5)*32 + (d&31))*480 + key]
            const float vals[4] = {v0, v1, v2, v3};
            #pragma unroll
            for (int c = 0; c < 4; ++c) {
                const int d = ob + c;
                out[((size_t)((l * 4 + (d >> 5)) * 32 + (d & 31))) * 480 + j] = f2bf(vals[c]);
            }
        } else {
            *(ushort4*)&out[(size_t)row * D + ob] =
                make_ushort4(f2bf(v0), f2bf(v1), f2bf(v2), f2bf(v3));
        }
    }
}

// Fused q/k/v LN+Linear, 128 rows/block (2 row-groups reuse the staged Wt).
// blocks [0,192): q  [192,432): k  [432,672): v.
__global__ __launch_bounds__(256, 4)
void ln_fused_kernel(const float* __restrict__ q, const float* __restrict__ k,
                     const float* __restrict__ v,
                     const unsigned short* __restrict__ Wt,
                     const float* __restrict__ c1, const float* __restrict__ c2,
                     unsigned short* __restrict__ qbuf,
                     unsigned short* __restrict__ kbuf,
                     unsigned short* __restrict__ vtb,
                     const float* __restrict__ scale_p)
{
    __shared__ __align__(16) unsigned short wlds[128 * WSTR];  // 34,816 B

    const int bid = blockIdx.x;
    const int t   = threadIdx.x;

    const unsigned short* Wsrc =
        (bid < 192) ? Wt : (bid < 432) ? (Wt + 16384) : (Wt + 32768);

    // stage 32KB Wt -> LDS, coalesced uint4, padded row stride
    {
        const uint4* ws = (const uint4*)Wsrc;     // 2048 x 16B
        #pragma unroll
        for (int i = 0; i < 8; ++i) {
            const int idx = i * 256 + t;
            const int r = idx >> 4, s = idx & 15;
            *(uint4*)&wlds[r * WSTR + s * 8] = ws[idx];
        }
    }
    __syncthreads();

    if (bid < 192) {
        // fold attn_scale * dh^-0.5 * log2(e) into q (softmax via exp2)
        const float s = scale_p[0] * 0.17677669529663687f * 1.4426950408889634f;
        const int rb = bid * 128;
        ln_body<384, 64, 8, 1>(q, wlds, c1, c2, qbuf, s, rb, t);
        ln_body<384, 64, 8, 1>(q, wlds, c1, c2, qbuf, s, rb + 64, t);
    } else if (bid < 432) {
        const int rb = (bid - 192) * 128;
        ln_body<480, 80, 10, 0>(k, wlds, c1 + 128, c2 + 128, kbuf, 1.0f, rb, t);
        ln_body<480, 80, 10, 0>(k, wlds, c1 + 128, c2 + 128, kbuf, 1.0f, rb + 64, t);
    } else {
        const int rb = (bid - 432) * 128;
        ln_body<480, 80, 10, 2>(v, wlds, c1 + 256, c2 + 256, vtb, 1.0f, rb, t);
        ln_body<480, 80, 10, 2>(v, wlds, c1 + 256, c2 + 256, vtb, 1.0f, rb + 64, t);
    }
}

// ---------------------------------------------------------------------------
// Flash attention, ZERO LDS. Grid (64 l, 4 h, 6 qz) x 256 thr (4 waves x 16q).
// The P transpose (C-layout -> B-frag) is done entirely in registers:
// target lane (m16,g) needs keys 8g..8g+7 of query m16 = two packed-dword
// pairs from source lanes m16+(g&1)*32 and +16, variant e0 (g<2) / e1 (g>=2).
// K/V fragments are software-prefetched one iteration ahead.
// No-max softmax via exp2 (log2e folded into q-projection).
// ---------------------------------------------------------------------------
__global__ __launch_bounds__(256, 4)
void attn_kernel(const unsigned short* __restrict__ qb,
                 const unsigned short* __restrict__ kb,
                 const unsigned short* __restrict__ vtb,
                 unsigned short* __restrict__ out)
{
    const int l    = blockIdx.x;
    const int h    = blockIdx.y;
    const int qz   = blockIdx.z;
    const int t    = threadIdx.x;
    const int wv   = t >> 6;
    const int lane = t & 63;
    const int m16  = lane & 15;
    const int g    = lane >> 4;

    const int qrow0 = qz * 64 + wv * 16;
    const short8 bq = *(const short8*)(
        qb + ((size_t)(l * 384 + qrow0 + m16)) * 128 + h * 32 + g * 8);

    const unsigned short* kbase = kb + ((size_t)l * 480) * 128 + h * 32;
    const unsigned short* vbase = vtb + ((size_t)(l * 4 + h) * 32) * 480;

    f32x4 o0 = {0.f, 0.f, 0.f, 0.f};
    f32x4 o1 = {0.f, 0.f, 0.f, 0.f};
    float esum = 0.f;

    const int srcA = m16 + (g & 1) * 32;
    const int srcB = srcA + 16;
    const bool lo  = (g < 2);

    // prefetch kc=0
    short8 a0n = *(const short8*)(kbase + (size_t)(m16) * 128 + g * 8);
    short8 a1n = *(const short8*)(kbase + (size_t)(16 + m16) * 128 + g * 8);
    short8 v0n = *(const short8*)(vbase + (size_t)m16 * 480 + g * 8);
    short8 v1n = *(const short8*)(vbase + (size_t)(16 + m16) * 480 + g * 8);

    for (int kc = 0; kc < 15; ++kc) {
        const short8 a0 = a0n, a1 = a1n, v0 = v0n, v1 = v1n;
        if (kc < 14) {
            const int kn = (kc + 1) * 32;
            a0n = *(const short8*)(kbase + (size_t)(kn + m16) * 128 + g * 8);
            a1n = *(const short8*)(kbase + (size_t)(kn + 16 + m16) * 128 + g * 8);
            v0n = *(const short8*)(vbase + (size_t)m16 * 480 + kn + g * 8);
            v1n = *(const short8*)(vbase + (size_t)(16 + m16) * 480 + kn + g * 8);
        }

        const f32x4 z = {0.f, 0.f, 0.f, 0.f};
        const f32x4 s0 = __builtin_amdgcn_mfma_f32_16x16x32_bf16(a0, bq, z, 0, 0, 0);
        const f32x4 s1 = __builtin_amdgcn_mfma_f32_16x16x32_bf16(a1, bq, z, 0, 0, 0);

        float e0[4], e1[4];
        #pragma unroll
        for (int r = 0; r < 4; ++r) {
            e0[r] = __builtin_amdgcn_exp2f(s0[r]);   // native v_exp_f32
            e1[r] = __builtin_amdgcn_exp2f(s1[r]);
            esum += e0[r] + e1[r];
        }

        // pack (lane holds keys 4g..4g+3 [e0] and 16+4g..+3 [e1], query m16)
        const unsigned pA0 = pack2(e0[0], e0[1]);
        const unsigned pA1 = pack2(e0[2], e0[3]);
        const unsigned pB0 = pack2(e1[0], e1[1]);
        const unsigned pB1 = pack2(e1[2], e1[3]);

        // register transpose: fetch both variants, select by target g
        const unsigned uA0 = __shfl(pA0, srcA, 64);
        const unsigned uA1 = __shfl(pA1, srcA, 64);
        const unsigned uA2 = __shfl(pA0, srcB, 64);
        const unsigned uA3 = __shfl(pA1, srcB, 64);
        const unsigned uB0 = __shfl(pB0, srcA, 64);
        const unsigned uB1 = __shfl(pB1, srcA, 64);
        const unsigned uB2 = __shfl(pB0, srcB, 64);
        const unsigned uB3 = __shfl(pB1, srcB, 64);

        union { unsigned u[4]; short8 s; } bp;
        bp.u[0] = lo ? uA0 : uB0;
        bp.u[1] = lo ? uA1 : uB1;
        bp.u[2] = lo ? uA2 : uB2;
        bp.u[3] = lo ? uA3 : uB3;

        o0 = __builtin_amdgcn_mfma_f32_16x16x32_bf16(v0, bp.s, o0, 0, 0, 0);
        o1 = __builtin_amdgcn_mfma_f32_16x16x32_bf16(v1, bp.s, o1, 0, 0, 0);
    }

    float lsum = esum;
    lsum += __shfl_xor(lsum, 16, 64);
    lsum += __shfl_xor(lsum, 32, 64);
    const float linv = 1.0f / lsum;

    unsigned short* ob = out + ((size_t)(l * 384 + qrow0 + m16)) * 128 + h * 32;
    *(ushort4*)(ob + g * 4) = make_ushort4(
        f2bf(o0[0] * linv), f2bf(o0[1] * linv), f2bf(o0[2] * linv), f2bf(o0[3] * linv));
    *(ushort4*)(ob + 16 + g * 4) = make_ushort4(
        f2bf(o1[0] * linv), f2bf(o1[1] * linv), f2bf(o1[2] * linv), f2bf(o1[3] * linv));
}

// ---------------------------------------------------------------------------
// proj (unchanged): mean over 6 views (bf16) -> @ Wp (MFMA) -> + bp + skip.
// 256 blocks x 256 thr.
// ---------------------------------------------------------------------------
__global__ __launch_bounds__(256)
void proj_kernel(const unsigned short* __restrict__ attnb,
                 const unsigned short* __restrict__ Wpt,
                 const float* __restrict__ bp,
                 const float* __restrict__ skip,
                 float* __restrict__ out)
{
    const int t    = threadIdx.x;
    const int wv   = t >> 6;        // out-quarter
    const int lane = t & 63;
    const int m16  = lane & 15;
    const int g    = lane >> 4;

    const int row  = blockIdx.x * 16 + m16;
    const int l    = row >> 6;
    const int qrem = row & 63;

    short8 xf[4];
    #pragma unroll
    for (int kt = 0; kt < 4; ++kt) {
        float m[8] = {0,0,0,0,0,0,0,0};
        #pragma unroll
        for (int n = 0; n < 6; ++n) {
            const short8 vv = *(const short8*)(
                attnb + ((size_t)(l * 384 + n * 64 + qrem)) * 128 + kt * 32 + g * 8);
            #pragma unroll
            for (int jj = 0; jj < 8; ++jj)
                m[jj] += bf2f((unsigned short)vv[jj]);
        }
        short8 pk;
        #pragma unroll
        for (int jj = 0; jj < 8; ++jj) pk[jj] = (short)f2bf(m[jj] * (1.0f / 6.0f));
        xf[kt] = pk;
    }

    f32x4 acc[2] = {{0,0,0,0},{0,0,0,0}};
    #pragma unroll
    for (int kt = 0; kt < 4; ++kt) {
        #pragma unroll
        for (int ot = 0; ot < 2; ++ot) {
            const short8 aw = *(const short8*)&Wpt[
                (size_t)((wv * 2 + ot) * 16 + m16) * 128 + kt * 32 + g * 8];
            acc[ot] = __builtin_amdgcn_mfma_f32_16x16x32_bf16(aw, xf[kt], acc[ot], 0, 0, 0);
        }
    }

    #pragma unroll
    for (int ot = 0; ot < 2; ++ot) {
        const int ob = (wv * 2 + ot) * 16 + g * 4;
        const float4 bb = *(const float4*)&bp[ob];
        const float4 sk = *(const float4*)&skip[(size_t)row * D + ob];
        float4 r;
        r.x = acc[ot][0] + bb.x + sk.x;
        r.y = acc[ot][1] + bb.y + sk.y;
        r.z = acc[ot][2] + bb.z + sk.z;
        r.w = acc[ot][3] + bb.w + sk.w;
        *(float4*)&out[(size_t)row * D + ob] = r;
    }
}

// ---------------------------------------------------------------------------
extern "C" void kernel_launch(void* const* d_in, const int* in_sizes, int n_in,
                              void* d_out, int out_size, void* d_ws, size_t ws_size,
                              hipStream_t stream)
{
    const float* q          = (const float*)d_in[0];
    const float* k          = (const float*)d_in[1];
    const float* v          = (const float*)d_in[2];
    const float* skip       = (const float*)d_in[3];
    const float* attn_scale = (const float*)d_in[4];
    const float* lnq_g      = (const float*)d_in[5];
    const float* lnq_b      = (const float*)d_in[6];
    const float* Wq         = (const float*)d_in[7];
    const float* bq         = (const float*)d_in[8];
    const float* lnk_g      = (const float*)d_in[9];
    const float* lnk_b      = (const float*)d_in[10];
    const float* Wk         = (const float*)d_in[11];
    const float* bk         = (const float*)d_in[12];
    const float* lnv_g      = (const float*)d_in[13];
    const float* lnv_b      = (const float*)d_in[14];
    const float* Wv         = (const float*)d_in[15];
    const float* bv         = (const float*)d_in[16];
    const float* Wp         = (const float*)d_in[17];
    const float* bp         = (const float*)d_in[18];

    float* out = (float*)d_out;
    char*  wsb = (char*)d_ws;

    // ws layout (bytes)
    unsigned short* qbuf  = (unsigned short*)(wsb);              //  6,291,456
    unsigned short* kbuf  = (unsigned short*)(wsb + 6291456);    //  7,864,320
    unsigned short* vtb   = (unsigned short*)(wsb + 14155776);   //  7,864,320
    unsigned short* Wt    = (unsigned short*)(wsb + 22020096);   //     98,304
    unsigned short* Wpt   = (unsigned short*)(wsb + 22118400);   //     32,768
    float*          c1    = (float*)        (wsb + 22151168);    //      1,536
    float*          c2    = (float*)        (wsb + 22152704);    //      1,536
    unsigned short* attnb = (unsigned short*)(wsb + 22154240);   //  6,291,456

    wprep_kernel<<<512, 64, 0, stream>>>(Wq, Wk, Wv, Wp,
                                         lnq_g, lnq_b, bq,
                                         lnk_g, lnk_b, bk,
                                         lnv_g, lnv_b, bv,
                                         (unsigned*)Wt, (unsigned*)Wpt, c1, c2);

    ln_fused_kernel<<<672, 256, 0, stream>>>(q, k, v, Wt, c1, c2,
                                             qbuf, kbuf, vtb, attn_scale);

    dim3 agrid(64, 4, 6);
    attn_kernel<<<agrid, 256, 0, stream>>>(qbuf, kbuf, vtb, attnb);

    proj_kernel<<<256, 256, 0, stream>>>(attnb, Wpt, bp, skip, out);
}

// Round 10
// 165.703 us; speedup vs baseline: 1.2552x; 1.2552x over previous
//
#include <hip/hip_runtime.h>

#define D 128
#define LN_EPS 1e-5f
#define WSTR 136    // Wt LDS row stride in shorts (272B = 17x16B: aligned, bank-min)

typedef __attribute__((ext_vector_type(8))) short short8;
typedef __attribute__((ext_vector_type(4))) float f32x4;

static __device__ __forceinline__ unsigned short f2bf(float f) {
    union { float f; unsigned u; } v; v.f = f;
    unsigned r = v.u + 0x7fffu + ((v.u >> 16) & 1u);   // RTNE
    return (unsigned short)(r >> 16);
}
static __device__ __forceinline__ unsigned pack2(float a, float b) {
    return (unsigned)f2bf(a) | ((unsigned)f2bf(b) << 16);
}
static __device__ __forceinline__ float bf2f(unsigned short u) {
    union { unsigned u; float f; } v; v.u = ((unsigned)u) << 16; return v.f;
}

// ---------------------------------------------------------------------------
// W prep: Wt = diag(g)W bf16 [out][in], c1 = g^T W, c2 = beta^T W + bias;
// Wpt = bf16 Wp^T.
// ---------------------------------------------------------------------------
__global__ __launch_bounds__(64)
void wprep_kernel(const float* __restrict__ Wq, const float* __restrict__ Wk,
                  const float* __restrict__ Wv, const float* __restrict__ Wp,
                  const float* __restrict__ gq, const float* __restrict__ betaq,
                  const float* __restrict__ biasq,
                  const float* __restrict__ gk, const float* __restrict__ betak,
                  const float* __restrict__ biask,
                  const float* __restrict__ gv, const float* __restrict__ betav,
                  const float* __restrict__ biasv,
                  unsigned* __restrict__ Wt, unsigned* __restrict__ Wpt,
                  float* __restrict__ c1, float* __restrict__ c2)
{
    const int id = blockIdx.x;
    const int w  = id >> 7;
    const int o  = id & 127;
    const int t  = threadIdx.x;
    if (w < 3) {
        const float* W  = (w == 0) ? Wq : (w == 1) ? Wk : Wv;
        const float* gg = (w == 0) ? gq : (w == 1) ? gk : gv;
        const float* bb = (w == 0) ? betaq : (w == 1) ? betak : betav;
        const float* bi = (w == 0) ? biasq : (w == 1) ? biask : biasv;
        const float w0 = W[(2 * t) * 128 + o];
        const float w1 = W[(2 * t + 1) * 128 + o];
        const float g0 = gg[2 * t], g1 = gg[2 * t + 1];
        const float b0 = bb[2 * t], b1 = bb[2 * t + 1];
        Wt[((size_t)w * 128 + o) * 64 + t] = pack2(g0 * w0, g1 * w1);
        float s1 = g0 * w0 + g1 * w1;
        float s2 = b0 * w0 + b1 * w1;
        #pragma unroll
        for (int off = 32; off > 0; off >>= 1) {
            s1 += __shfl_down(s1, off, 64);
            s2 += __shfl_down(s2, off, 64);
        }
        if (t == 0) { c1[w * 128 + o] = s1; c2[w * 128 + o] = s2 + bi[o]; }
    } else {
        Wpt[(size_t)o * 64 + t] = pack2(Wp[(2 * t) * 128 + o], Wp[(2 * t + 1) * 128 + o]);
    }
}

// ---------------------------------------------------------------------------
// LN+Linear body (64 rows per block — R8-proven; two bodies/block spilled at
// the compiler's 64-VGPR target, R9 regression). Wt staged in LDS by caller.
// Stats via X·1 and diag(X·X^T) MFMAs exchanged through LDS.
// NOTE: the smu/ssq exchange REQUIRES the __syncthreads(): the store is
// predicated and same-address as the load -> without a barrier LLVM
// store-forwards per-thread (R7 NaN failure).
// MODE 0: bf16 row-major. MODE 1: +scale (q). MODE 2: V^T scatter.
// ---------------------------------------------------------------------------
template<int PERL, int W1W2, int W2D, int MODE>
static __device__ __forceinline__
void ln_body(const float* __restrict__ in,
             const unsigned short* __restrict__ wlds,   // LDS, [128][WSTR]
             const float* __restrict__ c1, const float* __restrict__ c2,
             unsigned short* __restrict__ out,
             float scale, int rowbase, int t,
             float (*smu)[16], float (*ssq)[16])
{
    const int wv   = t >> 6;
    const int lane = t & 63;
    const int m16  = lane & 15;
    const int g    = lane >> 4;
    const int row  = rowbase + wv * 16 + m16;

    const int l   = row / PERL, j = row - l * PERL;
    const int n   = j / W1W2, rem = j - n * W1W2;
    const int w1  = rem / W2D, w2 = rem - w1 * W2D;
    const int X   = l >> 3, Y = l & 7;
    const float* xrow = in + ((size_t)(((n * 8 + X) * 8 + Y) * 8 + w1) * W2D + w2) * D;

    short8 xf[4];
    #pragma unroll
    for (int kt = 0; kt < 4; ++kt) {
        const float4 a = *(const float4*)(xrow + kt * 32 + g * 8);
        const float4 b = *(const float4*)(xrow + kt * 32 + g * 8 + 4);
        short8 vv;
        vv[0] = (short)f2bf(a.x); vv[1] = (short)f2bf(a.y);
        vv[2] = (short)f2bf(a.z); vv[3] = (short)f2bf(a.w);
        vv[4] = (short)f2bf(b.x); vv[5] = (short)f2bf(b.y);
        vv[6] = (short)f2bf(b.z); vv[7] = (short)f2bf(b.w);
        xf[kt] = vv;
    }

    short8 ones;
    #pragma unroll
    for (int jj = 0; jj < 8; ++jj) ones[jj] = (short)0x3F80;
    f32x4 sums = {0.f, 0.f, 0.f, 0.f}, gram = {0.f, 0.f, 0.f, 0.f};
    #pragma unroll
    for (int kt = 0; kt < 4; ++kt) {
        sums = __builtin_amdgcn_mfma_f32_16x16x32_bf16(xf[kt], ones, sums, 0, 0, 0);
        gram = __builtin_amdgcn_mfma_f32_16x16x32_bf16(xf[kt], xf[kt], gram, 0, 0, 0);
    }
    if (g == (m16 >> 2)) {
        smu[wv][m16] = sums[m16 & 3];
        ssq[wv][m16] = gram[m16 & 3];
    }
    __syncthreads();   // REQUIRED (see note above)
    const float mu   = smu[wv][m16] * (1.0f / 128.0f);
    const float msq  = ssq[wv][m16] * (1.0f / 128.0f);
    const float rstd = rsqrtf(msq - mu * mu + LN_EPS);
    const float rmu  = rstd * mu;

    f32x4 acc[8] = {{0,0,0,0},{0,0,0,0},{0,0,0,0},{0,0,0,0},
                    {0,0,0,0},{0,0,0,0},{0,0,0,0},{0,0,0,0}};
    #pragma unroll
    for (int kt = 0; kt < 4; ++kt) {
        #pragma unroll
        for (int ot = 0; ot < 8; ++ot) {
            const short8 aw = *(const short8*)&wlds[
                (ot * 16 + m16) * WSTR + kt * 32 + g * 8];
            acc[ot] = __builtin_amdgcn_mfma_f32_16x16x32_bf16(aw, xf[kt], acc[ot], 0, 0, 0);
        }
    }

    #pragma unroll
    for (int ot = 0; ot < 8; ++ot) {
        const int ob = ot * 16 + g * 4;
        const float4 cc1 = *(const float4*)&c1[ob];
        const float4 cc2 = *(const float4*)&c2[ob];
        float v0 = rstd * acc[ot][0] - rmu * cc1.x + cc2.x;
        float v1 = rstd * acc[ot][1] - rmu * cc1.y + cc2.y;
        float v2 = rstd * acc[ot][2] - rmu * cc1.z + cc2.z;
        float v3 = rstd * acc[ot][3] - rmu * cc1.w + cc2.w;
        if (MODE == 1) { v0 *= scale; v1 *= scale; v2 *= scale; v3 *= scale; }
        if (MODE == 2) {
            // transposed scatter: vtb[((l*4 + d>>5)*32 + (d&31))*480 + key]
            const float vals[4] = {v0, v1, v2, v3};
            #pragma unroll
            for (int c = 0; c < 4; ++c) {
                const int d = ob + c;
                out[((size_t)((l * 4 + (d >> 5)) * 32 + (d & 31))) * 480 + j] = f2bf(vals[c]);
            }
        } else {
            *(ushort4*)&out[(size_t)row * D + ob] =
                make_ushort4(f2bf(v0), f2bf(v1), f2bf(v2), f2bf(v3));
        }
    }
}

// Fused q/k/v LN+Linear (R8 structure). blocks [0,384): q  [384,864): k
// [864,1344): v. Stages the branch's 32KB Wt into LDS before the GEMM.
__global__ __launch_bounds__(256, 4)
void ln_fused_kernel(const float* __restrict__ q, const float* __restrict__ k,
                     const float* __restrict__ v,
                     const unsigned short* __restrict__ Wt,
                     const float* __restrict__ c1, const float* __restrict__ c2,
                     unsigned short* __restrict__ qbuf,
                     unsigned short* __restrict__ kbuf,
                     unsigned short* __restrict__ vtb,
                     const float* __restrict__ scale_p)
{
    __shared__ __align__(16) unsigned short wlds[128 * WSTR];  // 34,816 B
    __shared__ float smu[4][16];
    __shared__ float ssq[4][16];

    const int bid = blockIdx.x;
    const int t   = threadIdx.x;

    const unsigned short* Wsrc =
        (bid < 384) ? Wt : (bid < 864) ? (Wt + 16384) : (Wt + 32768);

    // stage 32KB Wt -> LDS, coalesced uint4, padded row stride
    {
        const uint4* ws = (const uint4*)Wsrc;     // 2048 x 16B
        #pragma unroll
        for (int i = 0; i < 8; ++i) {
            const int idx = i * 256 + t;
            const int r = idx >> 4, s = idx & 15;
            *(uint4*)&wlds[r * WSTR + s * 8] = ws[idx];
        }
    }
    __syncthreads();

    if (bid < 384) {
        // fold attn_scale * dh^-0.5 * log2(e) into q (softmax via exp2)
        const float s = scale_p[0] * 0.17677669529663687f * 1.4426950408889634f;
        ln_body<384, 64, 8, 1>(q, wlds, c1, c2, qbuf, s, bid * 64, t, smu, ssq);
    } else if (bid < 864) {
        ln_body<480, 80, 10, 0>(k, wlds, c1 + 128, c2 + 128, kbuf,
                                1.0f, (bid - 384) * 64, t, smu, ssq);
    } else {
        ln_body<480, 80, 10, 2>(v, wlds, c1 + 256, c2 + 256, vtb,
                                1.0f, (bid - 864) * 64, t, smu, ssq);
    }
}

// ---------------------------------------------------------------------------
// Flash attention, ZERO LDS (R9 version — kept). Grid (64 l, 4 h, 6 qz) x
// 256 thr (4 waves x 16q). P transpose (C-layout -> B-frag) entirely in
// registers via 8 shuffles + 4 selects; K/V prefetched one iter ahead.
// No-max softmax via exp2 (log2e folded into q-projection).
// ---------------------------------------------------------------------------
__global__ __launch_bounds__(256, 4)
void attn_kernel(const unsigned short* __restrict__ qb,
                 const unsigned short* __restrict__ kb,
                 const unsigned short* __restrict__ vtb,
                 unsigned short* __restrict__ out)
{
    const int l    = blockIdx.x;
    const int h    = blockIdx.y;
    const int qz   = blockIdx.z;
    const int t    = threadIdx.x;
    const int wv   = t >> 6;
    const int lane = t & 63;
    const int m16  = lane & 15;
    const int g    = lane >> 4;

    const int qrow0 = qz * 64 + wv * 16;
    const short8 bq = *(const short8*)(
        qb + ((size_t)(l * 384 + qrow0 + m16)) * 128 + h * 32 + g * 8);

    const unsigned short* kbase = kb + ((size_t)l * 480) * 128 + h * 32;
    const unsigned short* vbase = vtb + ((size_t)(l * 4 + h) * 32) * 480;

    f32x4 o0 = {0.f, 0.f, 0.f, 0.f};
    f32x4 o1 = {0.f, 0.f, 0.f, 0.f};
    float esum = 0.f;

    const int srcA = m16 + (g & 1) * 32;
    const int srcB = srcA + 16;
    const bool lo  = (g < 2);

    // prefetch kc=0
    short8 a0n = *(const short8*)(kbase + (size_t)(m16) * 128 + g * 8);
    short8 a1n = *(const short8*)(kbase + (size_t)(16 + m16) * 128 + g * 8);
    short8 v0n = *(const short8*)(vbase + (size_t)m16 * 480 + g * 8);
    short8 v1n = *(const short8*)(vbase + (size_t)(16 + m16) * 480 + g * 8);

    for (int kc = 0; kc < 15; ++kc) {
        const short8 a0 = a0n, a1 = a1n, v0 = v0n, v1 = v1n;
        if (kc < 14) {
            const int kn = (kc + 1) * 32;
            a0n = *(const short8*)(kbase + (size_t)(kn + m16) * 128 + g * 8);
            a1n = *(const short8*)(kbase + (size_t)(kn + 16 + m16) * 128 + g * 8);
            v0n = *(const short8*)(vbase + (size_t)m16 * 480 + kn + g * 8);
            v1n = *(const short8*)(vbase + (size_t)(16 + m16) * 480 + kn + g * 8);
        }

        const f32x4 z = {0.f, 0.f, 0.f, 0.f};
        const f32x4 s0 = __builtin_amdgcn_mfma_f32_16x16x32_bf16(a0, bq, z, 0, 0, 0);
        const f32x4 s1 = __builtin_amdgcn_mfma_f32_16x16x32_bf16(a1, bq, z, 0, 0, 0);

        float e0[4], e1[4];
        #pragma unroll
        for (int r = 0; r < 4; ++r) {
            e0[r] = __builtin_amdgcn_exp2f(s0[r]);   // native v_exp_f32
            e1[r] = __builtin_amdgcn_exp2f(s1[r]);
            esum += e0[r] + e1[r];
        }

        // pack (lane holds keys 4g..4g+3 [e0] and 16+4g..+3 [e1], query m16)
        const unsigned pA0 = pack2(e0[0], e0[1]);
        const unsigned pA1 = pack2(e0[2], e0[3]);
        const unsigned pB0 = pack2(e1[0], e1[1]);
        const unsigned pB1 = pack2(e1[2], e1[3]);

        // register transpose: fetch both variants, select by target g
        const unsigned uA0 = __shfl(pA0, srcA, 64);
        const unsigned uA1 = __shfl(pA1, srcA, 64);
        const unsigned uA2 = __shfl(pA0, srcB, 64);
        const unsigned uA3 = __shfl(pA1, srcB, 64);
        const unsigned uB0 = __shfl(pB0, srcA, 64);
        const unsigned uB1 = __shfl(pB1, srcA, 64);
        const unsigned uB2 = __shfl(pB0, srcB, 64);
        const unsigned uB3 = __shfl(pB1, srcB, 64);

        union { unsigned u[4]; short8 s; } bp;
        bp.u[0] = lo ? uA0 : uB0;
        bp.u[1] = lo ? uA1 : uB1;
        bp.u[2] = lo ? uA2 : uB2;
        bp.u[3] = lo ? uA3 : uB3;

        o0 = __builtin_amdgcn_mfma_f32_16x16x32_bf16(v0, bp.s, o0, 0, 0, 0);
        o1 = __builtin_amdgcn_mfma_f32_16x16x32_bf16(v1, bp.s, o1, 0, 0, 0);
    }

    float lsum = esum;
    lsum += __shfl_xor(lsum, 16, 64);
    lsum += __shfl_xor(lsum, 32, 64);
    const float linv = 1.0f / lsum;

    unsigned short* ob = out + ((size_t)(l * 384 + qrow0 + m16)) * 128 + h * 32;
    *(ushort4*)(ob + g * 4) = make_ushort4(
        f2bf(o0[0] * linv), f2bf(o0[1] * linv), f2bf(o0[2] * linv), f2bf(o0[3] * linv));
    *(ushort4*)(ob + 16 + g * 4) = make_ushort4(
        f2bf(o1[0] * linv), f2bf(o1[1] * linv), f2bf(o1[2] * linv), f2bf(o1[3] * linv));
}

// ---------------------------------------------------------------------------
// proj (unchanged): mean over 6 views (bf16) -> @ Wp (MFMA) -> + bp + skip.
// 256 blocks x 256 thr.
// ---------------------------------------------------------------------------
__global__ __launch_bounds__(256)
void proj_kernel(const unsigned short* __restrict__ attnb,
                 const unsigned short* __restrict__ Wpt,
                 const float* __restrict__ bp,
                 const float* __restrict__ skip,
                 float* __restrict__ out)
{
    const int t    = threadIdx.x;
    const int wv   = t >> 6;        // out-quarter
    const int lane = t & 63;
    const int m16  = lane & 15;
    const int g    = lane >> 4;

    const int row  = blockIdx.x * 16 + m16;
    const int l    = row >> 6;
    const int qrem = row & 63;

    short8 xf[4];
    #pragma unroll
    for (int kt = 0; kt < 4; ++kt) {
        float m[8] = {0,0,0,0,0,0,0,0};
        #pragma unroll
        for (int n = 0; n < 6; ++n) {
            const short8 vv = *(const short8*)(
                attnb + ((size_t)(l * 384 + n * 64 + qrem)) * 128 + kt * 32 + g * 8);
            #pragma unroll
            for (int jj = 0; jj < 8; ++jj)
                m[jj] += bf2f((unsigned short)vv[jj]);
        }
        short8 pk;
        #pragma unroll
        for (int jj = 0; jj < 8; ++jj) pk[jj] = (short)f2bf(m[jj] * (1.0f / 6.0f));
        xf[kt] = pk;
    }

    f32x4 acc[2] = {{0,0,0,0},{0,0,0,0}};
    #pragma unroll
    for (int kt = 0; kt < 4; ++kt) {
        #pragma unroll
        for (int ot = 0; ot < 2; ++ot) {
            const short8 aw = *(const short8*)&Wpt[
                (size_t)((wv * 2 + ot) * 16 + m16) * 128 + kt * 32 + g * 8];
            acc[ot] = __builtin_amdgcn_mfma_f32_16x16x32_bf16(aw, xf[kt], acc[ot], 0, 0, 0);
        }
    }

    #pragma unroll
    for (int ot = 0; ot < 2; ++ot) {
        const int ob = (wv * 2 + ot) * 16 + g * 4;
        const float4 bb = *(const float4*)&bp[ob];
        const float4 sk = *(const float4*)&skip[(size_t)row * D + ob];
        float4 r;
        r.x = acc[ot][0] + bb.x + sk.x;
        r.y = acc[ot][1] + bb.y + sk.y;
        r.z = acc[ot][2] + bb.z + sk.z;
        r.w = acc[ot][3] + bb.w + sk.w;
        *(float4*)&out[(size_t)row * D + ob] = r;
    }
}

// ---------------------------------------------------------------------------
extern "C" void kernel_launch(void* const* d_in, const int* in_sizes, int n_in,
                              void* d_out, int out_size, void* d_ws, size_t ws_size,
                              hipStream_t stream)
{
    const float* q          = (const float*)d_in[0];
    const float* k          = (const float*)d_in[1];
    const float* v          = (const float*)d_in[2];
    const float* skip       = (const float*)d_in[3];
    const float* attn_scale = (const float*)d_in[4];
    const float* lnq_g      = (const float*)d_in[5];
    const float* lnq_b      = (const float*)d_in[6];
    const float* Wq         = (const float*)d_in[7];
    const float* bq         = (const float*)d_in[8];
    const float* lnk_g      = (const float*)d_in[9];
    const float* lnk_b      = (const float*)d_in[10];
    const float* Wk         = (const float*)d_in[11];
    const float* bk         = (const float*)d_in[12];
    const float* lnv_g      = (const float*)d_in[13];
    const float* lnv_b      = (const float*)d_in[14];
    const float* Wv         = (const float*)d_in[15];
    const float* bv         = (const float*)d_in[16];
    const float* Wp         = (const float*)d_in[17];
    const float* bp         = (const float*)d_in[18];

    float* out = (float*)d_out;
    char*  wsb = (char*)d_ws;

    // ws layout (bytes)
    unsigned short* qbuf  = (unsigned short*)(wsb);              //  6,291,456
    unsigned short* kbuf  = (unsigned short*)(wsb + 6291456);    //  7,864,320
    unsigned short* vtb   = (unsigned short*)(wsb + 14155776);   //  7,864,320
    unsigned short* Wt    = (unsigned short*)(wsb + 22020096);   //     98,304
    unsigned short* Wpt   = (unsigned short*)(wsb + 22118400);   //     32,768
    float*          c1    = (float*)        (wsb + 22151168);    //      1,536
    float*          c2    = (float*)        (wsb + 22152704);    //      1,536
    unsigned short* attnb = (unsigned short*)(wsb + 22154240);   //  6,291,456

    wprep_kernel<<<512, 64, 0, stream>>>(Wq, Wk, Wv, Wp,
                                         lnq_g, lnq_b, bq,
                                         lnk_g, lnk_b, bk,
                                         lnv_g, lnv_b, bv,
                                         (unsigned*)Wt, (unsigned*)Wpt, c1, c2);

    ln_fused_kernel<<<1344, 256, 0, stream>>>(q, k, v, Wt, c1, c2,
                                              qbuf, kbuf, vtb, attn_scale);

    dim3 agrid(64, 4, 6);
    attn_kernel<<<agrid, 256, 0, stream>>>(qbuf, kbuf, vtb, attnb);

    proj_kernel<<<256, 256, 0, stream>>>(attnb, Wpt, bp, skip, out);
}

// Round 11
// 150.730 us; speedup vs baseline: 1.3799x; 1.0993x over previous
//
#include <hip/hip_runtime.h>

#define D 128
#define LN_EPS 1e-5f
#define WSTR 136    // Wt LDS row stride in shorts (272B = 17x16B: aligned, bank-min)

typedef __attribute__((ext_vector_type(8))) short short8;
typedef __attribute__((ext_vector_type(4))) float f32x4;

static __device__ __forceinline__ unsigned short f2bf(float f) {
    union { float f; unsigned u; } v; v.f = f;
    unsigned r = v.u + 0x7fffu + ((v.u >> 16) & 1u);   // RTNE
    return (unsigned short)(r >> 16);
}
static __device__ __forceinline__ unsigned pack2(float a, float b) {
    return (unsigned)f2bf(a) | ((unsigned)f2bf(b) << 16);
}
static __device__ __forceinline__ float bf2f(unsigned short u) {
    union { unsigned u; float f; } v; v.u = ((unsigned)u) << 16; return v.f;
}

// ---------------------------------------------------------------------------
// W prep: Wt = diag(g)W bf16 [out][in], c1 = g^T W, c2 = beta^T W + bias;
// Wpt = bf16 Wp^T.  (unchanged)
// ---------------------------------------------------------------------------
__global__ __launch_bounds__(64)
void wprep_kernel(const float* __restrict__ Wq, const float* __restrict__ Wk,
                  const float* __restrict__ Wv, const float* __restrict__ Wp,
                  const float* __restrict__ gq, const float* __restrict__ betaq,
                  const float* __restrict__ biasq,
                  const float* __restrict__ gk, const float* __restrict__ betak,
                  const float* __restrict__ biask,
                  const float* __restrict__ gv, const float* __restrict__ betav,
                  const float* __restrict__ biasv,
                  unsigned* __restrict__ Wt, unsigned* __restrict__ Wpt,
                  float* __restrict__ c1, float* __restrict__ c2)
{
    const int id = blockIdx.x;
    const int w  = id >> 7;
    const int o  = id & 127;
    const int t  = threadIdx.x;
    if (w < 3) {
        const float* W  = (w == 0) ? Wq : (w == 1) ? Wk : Wv;
        const float* gg = (w == 0) ? gq : (w == 1) ? gk : gv;
        const float* bb = (w == 0) ? betaq : (w == 1) ? betak : betav;
        const float* bi = (w == 0) ? biasq : (w == 1) ? biask : biasv;
        const float w0 = W[(2 * t) * 128 + o];
        const float w1 = W[(2 * t + 1) * 128 + o];
        const float g0 = gg[2 * t], g1 = gg[2 * t + 1];
        const float b0 = bb[2 * t], b1 = bb[2 * t + 1];
        Wt[((size_t)w * 128 + o) * 64 + t] = pack2(g0 * w0, g1 * w1);
        float s1 = g0 * w0 + g1 * w1;
        float s2 = b0 * w0 + b1 * w1;
        #pragma unroll
        for (int off = 32; off > 0; off >>= 1) {
            s1 += __shfl_down(s1, off, 64);
            s2 += __shfl_down(s2, off, 64);
        }
        if (t == 0) { c1[w * 128 + o] = s1; c2[w * 128 + o] = s2 + bi[o]; }
    } else {
        Wpt[(size_t)o * 64 + t] = pack2(Wp[(2 * t) * 128 + o], Wp[(2 * t + 1) * 128 + o]);
    }
}

// ---------------------------------------------------------------------------
// LN+Linear body (unchanged from R10 — proven). 64 rows per block.
// NOTE: the smu/ssq exchange REQUIRES the __syncthreads() (R7 NaN lesson).
// MODE 0: bf16 row-major. MODE 1: +scale (q). MODE 2: V^T scatter.
// ---------------------------------------------------------------------------
template<int PERL, int W1W2, int W2D, int MODE>
static __device__ __forceinline__
void ln_body(const float* __restrict__ in,
             const unsigned short* __restrict__ wlds,   // LDS, [128][WSTR]
             const float* __restrict__ c1, const float* __restrict__ c2,
             unsigned short* __restrict__ out,
             float scale, int rowbase, int t,
             float (*smu)[16], float (*ssq)[16])
{
    const int wv   = t >> 6;
    const int lane = t & 63;
    const int m16  = lane & 15;
    const int g    = lane >> 4;
    const int row  = rowbase + wv * 16 + m16;

    const int l   = row / PERL, j = row - l * PERL;
    const int n   = j / W1W2, rem = j - n * W1W2;
    const int w1  = rem / W2D, w2 = rem - w1 * W2D;
    const int X   = l >> 3, Y = l & 7;
    const float* xrow = in + ((size_t)(((n * 8 + X) * 8 + Y) * 8 + w1) * W2D + w2) * D;

    short8 xf[4];
    #pragma unroll
    for (int kt = 0; kt < 4; ++kt) {
        const float4 a = *(const float4*)(xrow + kt * 32 + g * 8);
        const float4 b = *(const float4*)(xrow + kt * 32 + g * 8 + 4);
        short8 vv;
        vv[0] = (short)f2bf(a.x); vv[1] = (short)f2bf(a.y);
        vv[2] = (short)f2bf(a.z); vv[3] = (short)f2bf(a.w);
        vv[4] = (short)f2bf(b.x); vv[5] = (short)f2bf(b.y);
        vv[6] = (short)f2bf(b.z); vv[7] = (short)f2bf(b.w);
        xf[kt] = vv;
    }

    short8 ones;
    #pragma unroll
    for (int jj = 0; jj < 8; ++jj) ones[jj] = (short)0x3F80;
    f32x4 sums = {0.f, 0.f, 0.f, 0.f}, gram = {0.f, 0.f, 0.f, 0.f};
    #pragma unroll
    for (int kt = 0; kt < 4; ++kt) {
        sums = __builtin_amdgcn_mfma_f32_16x16x32_bf16(xf[kt], ones, sums, 0, 0, 0);
        gram = __builtin_amdgcn_mfma_f32_16x16x32_bf16(xf[kt], xf[kt], gram, 0, 0, 0);
    }
    if (g == (m16 >> 2)) {
        smu[wv][m16] = sums[m16 & 3];
        ssq[wv][m16] = gram[m16 & 3];
    }
    __syncthreads();   // REQUIRED (R7 lesson)
    const float mu   = smu[wv][m16] * (1.0f / 128.0f);
    const float msq  = ssq[wv][m16] * (1.0f / 128.0f);
    const float rstd = rsqrtf(msq - mu * mu + LN_EPS);
    const float rmu  = rstd * mu;

    f32x4 acc[8] = {{0,0,0,0},{0,0,0,0},{0,0,0,0},{0,0,0,0},
                    {0,0,0,0},{0,0,0,0},{0,0,0,0},{0,0,0,0}};
    #pragma unroll
    for (int kt = 0; kt < 4; ++kt) {
        #pragma unroll
        for (int ot = 0; ot < 8; ++ot) {
            const short8 aw = *(const short8*)&wlds[
                (ot * 16 + m16) * WSTR + kt * 32 + g * 8];
            acc[ot] = __builtin_amdgcn_mfma_f32_16x16x32_bf16(aw, xf[kt], acc[ot], 0, 0, 0);
        }
    }

    #pragma unroll
    for (int ot = 0; ot < 8; ++ot) {
        const int ob = ot * 16 + g * 4;
        const float4 cc1 = *(const float4*)&c1[ob];
        const float4 cc2 = *(const float4*)&c2[ob];
        float v0 = rstd * acc[ot][0] - rmu * cc1.x + cc2.x;
        float v1 = rstd * acc[ot][1] - rmu * cc1.y + cc2.y;
        float v2 = rstd * acc[ot][2] - rmu * cc1.z + cc2.z;
        float v3 = rstd * acc[ot][3] - rmu * cc1.w + cc2.w;
        if (MODE == 1) { v0 *= scale; v1 *= scale; v2 *= scale; v3 *= scale; }
        if (MODE == 2) {
            const float vals[4] = {v0, v1, v2, v3};
            #pragma unroll
            for (int c = 0; c < 4; ++c) {
                const int d = ob + c;
                out[((size_t)((l * 4 + (d >> 5)) * 32 + (d & 31))) * 480 + j] = f2bf(vals[c]);
            }
        } else {
            *(ushort4*)&out[(size_t)row * D + ob] =
                make_ushort4(f2bf(v0), f2bf(v1), f2bf(v2), f2bf(v3));
        }
    }
}

// Fused q/k/v LN+Linear (unchanged from R10).
__global__ __launch_bounds__(256, 4)
void ln_fused_kernel(const float* __restrict__ q, const float* __restrict__ k,
                     const float* __restrict__ v,
                     const unsigned short* __restrict__ Wt,
                     const float* __restrict__ c1, const float* __restrict__ c2,
                     unsigned short* __restrict__ qbuf,
                     unsigned short* __restrict__ kbuf,
                     unsigned short* __restrict__ vtb,
                     const float* __restrict__ scale_p)
{
    __shared__ __align__(16) unsigned short wlds[128 * WSTR];  // 34,816 B
    __shared__ float smu[4][16];
    __shared__ float ssq[4][16];

    const int bid = blockIdx.x;
    const int t   = threadIdx.x;

    const unsigned short* Wsrc =
        (bid < 384) ? Wt : (bid < 864) ? (Wt + 16384) : (Wt + 32768);

    {
        const uint4* ws = (const uint4*)Wsrc;     // 2048 x 16B
        #pragma unroll
        for (int i = 0; i < 8; ++i) {
            const int idx = i * 256 + t;
            const int r = idx >> 4, s = idx & 15;
            *(uint4*)&wlds[r * WSTR + s * 8] = ws[idx];
        }
    }
    __syncthreads();

    if (bid < 384) {
        const float s = scale_p[0] * 0.17677669529663687f * 1.4426950408889634f;
        ln_body<384, 64, 8, 1>(q, wlds, c1, c2, qbuf, s, bid * 64, t, smu, ssq);
    } else if (bid < 864) {
        ln_body<480, 80, 10, 0>(k, wlds, c1 + 128, c2 + 128, kbuf,
                                1.0f, (bid - 384) * 64, t, smu, ssq);
    } else {
        ln_body<480, 80, 10, 2>(v, wlds, c1 + 256, c2 + 256, vtb,
                                1.0f, (bid - 864) * 64, t, smu, ssq);
    }
}

// ---------------------------------------------------------------------------
// Flash attention, zero LDS, K/V-shared q-tiles. Grid (64 l, 4 h, 2 qz) x
// 256 thr (4 waves x 16q x 3 q-tiles). Each prefetched K/V chunk feeds SIX
// MFMAs (3 q-tiles x QK,PV pair) instead of two -> 3x less global traffic,
// 3x ILP per load. Register P transpose (8 shfl + 4 selects per q-tile).
// No-max softmax via exp2 (log2e folded into q-projection).
// ---------------------------------------------------------------------------
__global__ __launch_bounds__(256, 4)
void attn_kernel(const unsigned short* __restrict__ qb,
                 const unsigned short* __restrict__ kb,
                 const unsigned short* __restrict__ vtb,
                 unsigned short* __restrict__ out)
{
    const int l    = blockIdx.x;
    const int h    = blockIdx.y;
    const int qz   = blockIdx.z;    // 0..1
    const int t    = threadIdx.x;
    const int wv   = t >> 6;
    const int lane = t & 63;
    const int m16  = lane & 15;
    const int g    = lane >> 4;

    // 3 q-tiles per wave: rows qz*192 + qt*64 + wv*16 + m16
    short8 bq[3];
    #pragma unroll
    for (int qt = 0; qt < 3; ++qt) {
        const int qrow0 = qz * 192 + qt * 64 + wv * 16;
        bq[qt] = *(const short8*)(
            qb + ((size_t)(l * 384 + qrow0 + m16)) * 128 + h * 32 + g * 8);
    }

    const unsigned short* kbase = kb + ((size_t)l * 480) * 128 + h * 32;
    const unsigned short* vbase = vtb + ((size_t)(l * 4 + h) * 32) * 480;

    f32x4 o0[3] = {{0,0,0,0},{0,0,0,0},{0,0,0,0}};
    f32x4 o1[3] = {{0,0,0,0},{0,0,0,0},{0,0,0,0}};
    float esum[3] = {0.f, 0.f, 0.f};

    const int srcA = m16 + (g & 1) * 32;
    const int srcB = srcA + 16;
    const bool lo  = (g < 2);

    // prefetch kc=0
    short8 a0n = *(const short8*)(kbase + (size_t)(m16) * 128 + g * 8);
    short8 a1n = *(const short8*)(kbase + (size_t)(16 + m16) * 128 + g * 8);
    short8 v0n = *(const short8*)(vbase + (size_t)m16 * 480 + g * 8);
    short8 v1n = *(const short8*)(vbase + (size_t)(16 + m16) * 480 + g * 8);

    for (int kc = 0; kc < 15; ++kc) {
        const short8 a0 = a0n, a1 = a1n, v0 = v0n, v1 = v1n;
        if (kc < 14) {
            const int kn = (kc + 1) * 32;
            a0n = *(const short8*)(kbase + (size_t)(kn + m16) * 128 + g * 8);
            a1n = *(const short8*)(kbase + (size_t)(kn + 16 + m16) * 128 + g * 8);
            v0n = *(const short8*)(vbase + (size_t)m16 * 480 + kn + g * 8);
            v1n = *(const short8*)(vbase + (size_t)(16 + m16) * 480 + kn + g * 8);
        }

        #pragma unroll
        for (int qt = 0; qt < 3; ++qt) {
            const f32x4 z = {0.f, 0.f, 0.f, 0.f};
            const f32x4 s0 = __builtin_amdgcn_mfma_f32_16x16x32_bf16(a0, bq[qt], z, 0, 0, 0);
            const f32x4 s1 = __builtin_amdgcn_mfma_f32_16x16x32_bf16(a1, bq[qt], z, 0, 0, 0);

            float e0[4], e1[4];
            float es = 0.f;
            #pragma unroll
            for (int r = 0; r < 4; ++r) {
                e0[r] = __builtin_amdgcn_exp2f(s0[r]);
                e1[r] = __builtin_amdgcn_exp2f(s1[r]);
                es += e0[r] + e1[r];
            }
            esum[qt] += es;

            const unsigned pA0 = pack2(e0[0], e0[1]);
            const unsigned pA1 = pack2(e0[2], e0[3]);
            const unsigned pB0 = pack2(e1[0], e1[1]);
            const unsigned pB1 = pack2(e1[2], e1[3]);

            const unsigned uA0 = __shfl(pA0, srcA, 64);
            const unsigned uA1 = __shfl(pA1, srcA, 64);
            const unsigned uA2 = __shfl(pA0, srcB, 64);
            const unsigned uA3 = __shfl(pA1, srcB, 64);
            const unsigned uB0 = __shfl(pB0, srcA, 64);
            const unsigned uB1 = __shfl(pB1, srcA, 64);
            const unsigned uB2 = __shfl(pB0, srcB, 64);
            const unsigned uB3 = __shfl(pB1, srcB, 64);

            union { unsigned u[4]; short8 s; } bp;
            bp.u[0] = lo ? uA0 : uB0;
            bp.u[1] = lo ? uA1 : uB1;
            bp.u[2] = lo ? uA2 : uB2;
            bp.u[3] = lo ? uA3 : uB3;

            o0[qt] = __builtin_amdgcn_mfma_f32_16x16x32_bf16(v0, bp.s, o0[qt], 0, 0, 0);
            o1[qt] = __builtin_amdgcn_mfma_f32_16x16x32_bf16(v1, bp.s, o1[qt], 0, 0, 0);
        }
    }

    #pragma unroll
    for (int qt = 0; qt < 3; ++qt) {
        float lsum = esum[qt];
        lsum += __shfl_xor(lsum, 16, 64);
        lsum += __shfl_xor(lsum, 32, 64);
        const float linv = 1.0f / lsum;

        const int qrow0 = qz * 192 + qt * 64 + wv * 16;
        unsigned short* ob = out + ((size_t)(l * 384 + qrow0 + m16)) * 128 + h * 32;
        *(ushort4*)(ob + g * 4) = make_ushort4(
            f2bf(o0[qt][0] * linv), f2bf(o0[qt][1] * linv),
            f2bf(o0[qt][2] * linv), f2bf(o0[qt][3] * linv));
        *(ushort4*)(ob + 16 + g * 4) = make_ushort4(
            f2bf(o1[qt][0] * linv), f2bf(o1[qt][1] * linv),
            f2bf(o1[qt][2] * linv), f2bf(o1[qt][3] * linv));
    }
}

// ---------------------------------------------------------------------------
// proj (unchanged): mean over 6 views (bf16) -> @ Wp (MFMA) -> + bp + skip.
// ---------------------------------------------------------------------------
__global__ __launch_bounds__(256)
void proj_kernel(const unsigned short* __restrict__ attnb,
                 const unsigned short* __restrict__ Wpt,
                 const float* __restrict__ bp,
                 const float* __restrict__ skip,
                 float* __restrict__ out)
{
    const int t    = threadIdx.x;
    const int wv   = t >> 6;        // out-quarter
    const int lane = t & 63;
    const int m16  = lane & 15;
    const int g    = lane >> 4;

    const int row  = blockIdx.x * 16 + m16;
    const int l    = row >> 6;
    const int qrem = row & 63;

    short8 xf[4];
    #pragma unroll
    for (int kt = 0; kt < 4; ++kt) {
        float m[8] = {0,0,0,0,0,0,0,0};
        #pragma unroll
        for (int n = 0; n < 6; ++n) {
            const short8 vv = *(const short8*)(
                attnb + ((size_t)(l * 384 + n * 64 + qrem)) * 128 + kt * 32 + g * 8);
            #pragma unroll
            for (int jj = 0; jj < 8; ++jj)
                m[jj] += bf2f((unsigned short)vv[jj]);
        }
        short8 pk;
        #pragma unroll
        for (int jj = 0; jj < 8; ++jj) pk[jj] = (short)f2bf(m[jj] * (1.0f / 6.0f));
        xf[kt] = pk;
    }

    f32x4 acc[2] = {{0,0,0,0},{0,0,0,0}};
    #pragma unroll
    for (int kt = 0; kt < 4; ++kt) {
        #pragma unroll
        for (int ot = 0; ot < 2; ++ot) {
            const short8 aw = *(const short8*)&Wpt[
                (size_t)((wv * 2 + ot) * 16 + m16) * 128 + kt * 32 + g * 8];
            acc[ot] = __builtin_amdgcn_mfma_f32_16x16x32_bf16(aw, xf[kt], acc[ot], 0, 0, 0);
        }
    }

    #pragma unroll
    for (int ot = 0; ot < 2; ++ot) {
        const int ob = (wv * 2 + ot) * 16 + g * 4;
        const float4 bb = *(const float4*)&bp[ob];
        const float4 sk = *(const float4*)&skip[(size_t)row * D + ob];
        float4 r;
        r.x = acc[ot][0] + bb.x + sk.x;
        r.y = acc[ot][1] + bb.y + sk.y;
        r.z = acc[ot][2] + bb.z + sk.z;
        r.w = acc[ot][3] + bb.w + sk.w;
        *(float4*)&out[(size_t)row * D + ob] = r;
    }
}

// ---------------------------------------------------------------------------
extern "C" void kernel_launch(void* const* d_in, const int* in_sizes, int n_in,
                              void* d_out, int out_size, void* d_ws, size_t ws_size,
                              hipStream_t stream)
{
    const float* q          = (const float*)d_in[0];
    const float* k          = (const float*)d_in[1];
    const float* v          = (const float*)d_in[2];
    const float* skip       = (const float*)d_in[3];
    const float* attn_scale = (const float*)d_in[4];
    const float* lnq_g      = (const float*)d_in[5];
    const float* lnq_b      = (const float*)d_in[6];
    const float* Wq         = (const float*)d_in[7];
    const float* bq         = (const float*)d_in[8];
    const float* lnk_g      = (const float*)d_in[9];
    const float* lnk_b      = (const float*)d_in[10];
    const float* Wk         = (const float*)d_in[11];
    const float* bk         = (const float*)d_in[12];
    const float* lnv_g      = (const float*)d_in[13];
    const float* lnv_b      = (const float*)d_in[14];
    const float* Wv         = (const float*)d_in[15];
    const float* bv         = (const float*)d_in[16];
    const float* Wp         = (const float*)d_in[17];
    const float* bp         = (const float*)d_in[18];

    float* out = (float*)d_out;
    char*  wsb = (char*)d_ws;

    // ws layout (bytes)
    unsigned short* qbuf  = (unsigned short*)(wsb);              //  6,291,456
    unsigned short* kbuf  = (unsigned short*)(wsb + 6291456);    //  7,864,320
    unsigned short* vtb   = (unsigned short*)(wsb + 14155776);   //  7,864,320
    unsigned short* Wt    = (unsigned short*)(wsb + 22020096);   //     98,304
    unsigned short* Wpt   = (unsigned short*)(wsb + 22118400);   //     32,768
    float*          c1    = (float*)        (wsb + 22151168);    //      1,536
    float*          c2    = (float*)        (wsb + 22152704);    //      1,536
    unsigned short* attnb = (unsigned short*)(wsb + 22154240);   //  6,291,456

    wprep_kernel<<<512, 64, 0, stream>>>(Wq, Wk, Wv, Wp,
                                         lnq_g, lnq_b, bq,
                                         lnk_g, lnk_b, bk,
                                         lnv_g, lnv_b, bv,
                                         (unsigned*)Wt, (unsigned*)Wpt, c1, c2);

    ln_fused_kernel<<<1344, 256, 0, stream>>>(q, k, v, Wt, c1, c2,
                                              qbuf, kbuf, vtb, attn_scale);

    dim3 agrid(64, 4, 2);
    attn_kernel<<<agrid, 256, 0, stream>>>(qbuf, kbuf, vtb, attnb);

    proj_kernel<<<256, 256, 0, stream>>>(attnb, Wpt, bp, skip, out);
}

// Round 13
// 145.622 us; speedup vs baseline: 1.4283x; 1.0351x over previous
//
#include <hip/hip_runtime.h>

#define D 128
#define LN_EPS 1e-5f
#define WSTR 136    // Wt LDS row stride in shorts (272B = 17x16B: aligned, bank-min)

typedef __attribute__((ext_vector_type(8))) short short8;
typedef __attribute__((ext_vector_type(4))) float f32x4;

static __device__ __forceinline__ unsigned short f2bf(float f) {
    union { float f; unsigned u; } v; v.f = f;
    unsigned r = v.u + 0x7fffu + ((v.u >> 16) & 1u);   // RTNE
    return (unsigned short)(r >> 16);
}
static __device__ __forceinline__ unsigned pack2(float a, float b) {
    return (unsigned)f2bf(a) | ((unsigned)f2bf(b) << 16);
}
static __device__ __forceinline__ float bf2f(unsigned short u) {
    union { unsigned u; float f; } v; v.u = ((unsigned)u) << 16; return v.f;
}

// ---------------------------------------------------------------------------
// W prep: Wt = diag(g)W bf16 [out][in], c1 = g^T W, c2 = beta^T W + bias;
// Wpt = bf16 Wp^T.  (unchanged)
// ---------------------------------------------------------------------------
__global__ __launch_bounds__(64)
void wprep_kernel(const float* __restrict__ Wq, const float* __restrict__ Wk,
                  const float* __restrict__ Wv, const float* __restrict__ Wp,
                  const float* __restrict__ gq, const float* __restrict__ betaq,
                  const float* __restrict__ biasq,
                  const float* __restrict__ gk, const float* __restrict__ betak,
                  const float* __restrict__ biask,
                  const float* __restrict__ gv, const float* __restrict__ betav,
                  const float* __restrict__ biasv,
                  unsigned* __restrict__ Wt, unsigned* __restrict__ Wpt,
                  float* __restrict__ c1, float* __restrict__ c2)
{
    const int id = blockIdx.x;
    const int w  = id >> 7;
    const int o  = id & 127;
    const int t  = threadIdx.x;
    if (w < 3) {
        const float* W  = (w == 0) ? Wq : (w == 1) ? Wk : Wv;
        const float* gg = (w == 0) ? gq : (w == 1) ? gk : gv;
        const float* bb = (w == 0) ? betaq : (w == 1) ? betak : betav;
        const float* bi = (w == 0) ? biasq : (w == 1) ? biask : biasv;
        const float w0 = W[(2 * t) * 128 + o];
        const float w1 = W[(2 * t + 1) * 128 + o];
        const float g0 = gg[2 * t], g1 = gg[2 * t + 1];
        const float b0 = bb[2 * t], b1 = bb[2 * t + 1];
        Wt[((size_t)w * 128 + o) * 64 + t] = pack2(g0 * w0, g1 * w1);
        float s1 = g0 * w0 + g1 * w1;
        float s2 = b0 * w0 + b1 * w1;
        #pragma unroll
        for (int off = 32; off > 0; off >>= 1) {
            s1 += __shfl_down(s1, off, 64);
            s2 += __shfl_down(s2, off, 64);
        }
        if (t == 0) { c1[w * 128 + o] = s1; c2[w * 128 + o] = s2 + bi[o]; }
    } else {
        Wpt[(size_t)o * 64 + t] = pack2(Wp[(2 * t) * 128 + o], Wp[(2 * t + 1) * 128 + o]);
    }
}

// ---------------------------------------------------------------------------
// LN+Linear body (unchanged — proven). 64 rows per block.
// NOTE: the smu/ssq exchange REQUIRES the __syncthreads() (R7 NaN lesson).
// MODE 0: bf16 row-major. MODE 1: +scale (q). MODE 2: V^T scatter.
// ---------------------------------------------------------------------------
template<int PERL, int W1W2, int W2D, int MODE>
static __device__ __forceinline__
void ln_body(const float* __restrict__ in,
             const unsigned short* __restrict__ wlds,   // LDS, [128][WSTR]
             const float* __restrict__ c1, const float* __restrict__ c2,
             unsigned short* __restrict__ out,
             float scale, int rowbase, int t,
             float (*smu)[16], float (*ssq)[16])
{
    const int wv   = t >> 6;
    const int lane = t & 63;
    const int m16  = lane & 15;
    const int g    = lane >> 4;
    const int row  = rowbase + wv * 16 + m16;

    const int l   = row / PERL, j = row - l * PERL;
    const int n   = j / W1W2, rem = j - n * W1W2;
    const int w1  = rem / W2D, w2 = rem - w1 * W2D;
    const int X   = l >> 3, Y = l & 7;
    const float* xrow = in + ((size_t)(((n * 8 + X) * 8 + Y) * 8 + w1) * W2D + w2) * D;

    short8 xf[4];
    #pragma unroll
    for (int kt = 0; kt < 4; ++kt) {
        const float4 a = *(const float4*)(xrow + kt * 32 + g * 8);
        const float4 b = *(const float4*)(xrow + kt * 32 + g * 8 + 4);
        short8 vv;
        vv[0] = (short)f2bf(a.x); vv[1] = (short)f2bf(a.y);
        vv[2] = (short)f2bf(a.z); vv[3] = (short)f2bf(a.w);
        vv[4] = (short)f2bf(b.x); vv[5] = (short)f2bf(b.y);
        vv[6] = (short)f2bf(b.z); vv[7] = (short)f2bf(b.w);
        xf[kt] = vv;
    }

    short8 ones;
    #pragma unroll
    for (int jj = 0; jj < 8; ++jj) ones[jj] = (short)0x3F80;
    f32x4 sums = {0.f, 0.f, 0.f, 0.f}, gram = {0.f, 0.f, 0.f, 0.f};
    #pragma unroll
    for (int kt = 0; kt < 4; ++kt) {
        sums = __builtin_amdgcn_mfma_f32_16x16x32_bf16(xf[kt], ones, sums, 0, 0, 0);
        gram = __builtin_amdgcn_mfma_f32_16x16x32_bf16(xf[kt], xf[kt], gram, 0, 0, 0);
    }
    if (g == (m16 >> 2)) {
        smu[wv][m16] = sums[m16 & 3];
        ssq[wv][m16] = gram[m16 & 3];
    }
    __syncthreads();   // REQUIRED (R7 lesson)
    const float mu   = smu[wv][m16] * (1.0f / 128.0f);
    const float msq  = ssq[wv][m16] * (1.0f / 128.0f);
    const float rstd = rsqrtf(msq - mu * mu + LN_EPS);
    const float rmu  = rstd * mu;

    f32x4 acc[8] = {{0,0,0,0},{0,0,0,0},{0,0,0,0},{0,0,0,0},
                    {0,0,0,0},{0,0,0,0},{0,0,0,0},{0,0,0,0}};
    #pragma unroll
    for (int kt = 0; kt < 4; ++kt) {
        #pragma unroll
        for (int ot = 0; ot < 8; ++ot) {
            const short8 aw = *(const short8*)&wlds[
                (ot * 16 + m16) * WSTR + kt * 32 + g * 8];
            acc[ot] = __builtin_amdgcn_mfma_f32_16x16x32_bf16(aw, xf[kt], acc[ot], 0, 0, 0);
        }
    }

    #pragma unroll
    for (int ot = 0; ot < 8; ++ot) {
        const int ob = ot * 16 + g * 4;
        const float4 cc1 = *(const float4*)&c1[ob];
        const float4 cc2 = *(const float4*)&c2[ob];
        float v0 = rstd * acc[ot][0] - rmu * cc1.x + cc2.x;
        float v1 = rstd * acc[ot][1] - rmu * cc1.y + cc2.y;
        float v2 = rstd * acc[ot][2] - rmu * cc1.z + cc2.z;
        float v3 = rstd * acc[ot][3] - rmu * cc1.w + cc2.w;
        if (MODE == 1) { v0 *= scale; v1 *= scale; v2 *= scale; v3 *= scale; }
        if (MODE == 2) {
            const float vals[4] = {v0, v1, v2, v3};
            #pragma unroll
            for (int c = 0; c < 4; ++c) {
                const int d = ob + c;
                out[((size_t)((l * 4 + (d >> 5)) * 32 + (d & 31))) * 480 + j] = f2bf(vals[c]);
            }
        } else {
            *(ushort4*)&out[(size_t)row * D + ob] =
                make_ushort4(f2bf(v0), f2bf(v1), f2bf(v2), f2bf(v3));
        }
    }
}

// Fused q/k/v LN+Linear (unchanged).
__global__ __launch_bounds__(256, 4)
void ln_fused_kernel(const float* __restrict__ q, const float* __restrict__ k,
                     const float* __restrict__ v,
                     const unsigned short* __restrict__ Wt,
                     const float* __restrict__ c1, const float* __restrict__ c2,
                     unsigned short* __restrict__ qbuf,
                     unsigned short* __restrict__ kbuf,
                     unsigned short* __restrict__ vtb,
                     const float* __restrict__ scale_p)
{
    __shared__ __align__(16) unsigned short wlds[128 * WSTR];  // 34,816 B
    __shared__ float smu[4][16];
    __shared__ float ssq[4][16];

    const int bid = blockIdx.x;
    const int t   = threadIdx.x;

    const unsigned short* Wsrc =
        (bid < 384) ? Wt : (bid < 864) ? (Wt + 16384) : (Wt + 32768);

    {
        const uint4* ws = (const uint4*)Wsrc;     // 2048 x 16B
        #pragma unroll
        for (int i = 0; i < 8; ++i) {
            const int idx = i * 256 + t;
            const int r = idx >> 4, s = idx & 15;
            *(uint4*)&wlds[r * WSTR + s * 8] = ws[idx];
        }
    }
    __syncthreads();

    if (bid < 384) {
        const float s = scale_p[0] * 0.17677669529663687f * 1.4426950408889634f;
        ln_body<384, 64, 8, 1>(q, wlds, c1, c2, qbuf, s, bid * 64, t, smu, ssq);
    } else if (bid < 864) {
        ln_body<480, 80, 10, 0>(k, wlds, c1 + 128, c2 + 128, kbuf,
                                1.0f, (bid - 384) * 64, t, smu, ssq);
    } else {
        ln_body<480, 80, 10, 2>(v, wlds, c1 + 256, c2 + 256, vtb,
                                1.0f, (bid - 864) * 64, t, smu, ssq);
    }
}

// ---------------------------------------------------------------------------
// Flash attention, zero LDS, K/V-shared q-tiles + in-register view-mean.
// Grid (64 l, 4 h, 2 qz) x 256 thr. q-tile qt is view n = qz*3+qt of the
// SAME 64 query positions (pos = wv*16+m16) -> epilogue sums the 3
// normalized views in registers; writes ONE partial row per (qz,l,pos) to
// pmean[qz] (4096 rows x 128 each).
// ---------------------------------------------------------------------------
__global__ __launch_bounds__(256, 4)
void attn_kernel(const unsigned short* __restrict__ qb,
                 const unsigned short* __restrict__ kb,
                 const unsigned short* __restrict__ vtb,
                 unsigned short* __restrict__ pmean)   // [2][4096][128] bf16
{
    const int l    = blockIdx.x;
    const int h    = blockIdx.y;
    const int qz   = blockIdx.z;    // 0..1
    const int t    = threadIdx.x;
    const int wv   = t >> 6;
    const int lane = t & 63;
    const int m16  = lane & 15;
    const int g    = lane >> 4;

    // 3 q-tiles per wave: rows qz*192 + qt*64 + wv*16 + m16 (view n=qz*3+qt)
    short8 bq[3];
    #pragma unroll
    for (int qt = 0; qt < 3; ++qt) {
        const int qrow0 = qz * 192 + qt * 64 + wv * 16;
        bq[qt] = *(const short8*)(
            qb + ((size_t)(l * 384 + qrow0 + m16)) * 128 + h * 32 + g * 8);
    }

    const unsigned short* kbase = kb + ((size_t)l * 480) * 128 + h * 32;
    const unsigned short* vbase = vtb + ((size_t)(l * 4 + h) * 32) * 480;

    f32x4 o0[3] = {{0,0,0,0},{0,0,0,0},{0,0,0,0}};
    f32x4 o1[3] = {{0,0,0,0},{0,0,0,0},{0,0,0,0}};
    float esum[3] = {0.f, 0.f, 0.f};

    const int srcA = m16 + (g & 1) * 32;
    const int srcB = srcA + 16;
    const bool lo  = (g < 2);

    // prefetch kc=0
    short8 a0n = *(const short8*)(kbase + (size_t)(m16) * 128 + g * 8);
    short8 a1n = *(const short8*)(kbase + (size_t)(16 + m16) * 128 + g * 8);
    short8 v0n = *(const short8*)(vbase + (size_t)m16 * 480 + g * 8);
    short8 v1n = *(const short8*)(vbase + (size_t)(16 + m16) * 480 + g * 8);

    for (int kc = 0; kc < 15; ++kc) {
        const short8 a0 = a0n, a1 = a1n, v0 = v0n, v1 = v1n;
        if (kc < 14) {
            const int kn = (kc + 1) * 32;
            a0n = *(const short8*)(kbase + (size_t)(kn + m16) * 128 + g * 8);
            a1n = *(const short8*)(kbase + (size_t)(kn + 16 + m16) * 128 + g * 8);
            v0n = *(const short8*)(vbase + (size_t)m16 * 480 + kn + g * 8);
            v1n = *(const short8*)(vbase + (size_t)(16 + m16) * 480 + kn + g * 8);
        }

        #pragma unroll
        for (int qt = 0; qt < 3; ++qt) {
            const f32x4 z = {0.f, 0.f, 0.f, 0.f};
            const f32x4 s0 = __builtin_amdgcn_mfma_f32_16x16x32_bf16(a0, bq[qt], z, 0, 0, 0);
            const f32x4 s1 = __builtin_amdgcn_mfma_f32_16x16x32_bf16(a1, bq[qt], z, 0, 0, 0);

            float e0[4], e1[4];
            float es = 0.f;
            #pragma unroll
            for (int r = 0; r < 4; ++r) {
                e0[r] = __builtin_amdgcn_exp2f(s0[r]);
                e1[r] = __builtin_amdgcn_exp2f(s1[r]);
                es += e0[r] + e1[r];
            }
            esum[qt] += es;

            const unsigned pA0 = pack2(e0[0], e0[1]);
            const unsigned pA1 = pack2(e0[2], e0[3]);
            const unsigned pB0 = pack2(e1[0], e1[1]);
            const unsigned pB1 = pack2(e1[2], e1[3]);

            const unsigned uA0 = __shfl(pA0, srcA, 64);
            const unsigned uA1 = __shfl(pA1, srcA, 64);
            const unsigned uA2 = __shfl(pA0, srcB, 64);
            const unsigned uA3 = __shfl(pA1, srcB, 64);
            const unsigned uB0 = __shfl(pB0, srcA, 64);
            const unsigned uB1 = __shfl(pB1, srcA, 64);
            const unsigned uB2 = __shfl(pB0, srcB, 64);
            const unsigned uB3 = __shfl(pB1, srcB, 64);

            union { unsigned u[4]; short8 s; } bp;
            bp.u[0] = lo ? uA0 : uB0;
            bp.u[1] = lo ? uA1 : uB1;
            bp.u[2] = lo ? uA2 : uB2;
            bp.u[3] = lo ? uA3 : uB3;

            o0[qt] = __builtin_amdgcn_mfma_f32_16x16x32_bf16(v0, bp.s, o0[qt], 0, 0, 0);
            o1[qt] = __builtin_amdgcn_mfma_f32_16x16x32_bf16(v1, bp.s, o1[qt], 0, 0, 0);
        }
    }

    // epilogue: normalize each view, sum the 3 views in registers
    f32x4 om0 = {0.f, 0.f, 0.f, 0.f};
    f32x4 om1 = {0.f, 0.f, 0.f, 0.f};
    #pragma unroll
    for (int qt = 0; qt < 3; ++qt) {
        float lsum = esum[qt];
        lsum += __shfl_xor(lsum, 16, 64);
        lsum += __shfl_xor(lsum, 32, 64);
        const float linv = 1.0f / lsum;
        #pragma unroll
        for (int r = 0; r < 4; ++r) {
            om0[r] += o0[qt][r] * linv;
            om1[r] += o1[qt][r] * linv;
        }
    }

    const int pos = wv * 16 + m16;
    unsigned short* ob = pmean + ((size_t)qz * 4096 + l * 64 + pos) * 128 + h * 32;
    *(ushort4*)(ob + g * 4) = make_ushort4(
        f2bf(om0[0]), f2bf(om0[1]), f2bf(om0[2]), f2bf(om0[3]));
    *(ushort4*)(ob + 16 + g * 4) = make_ushort4(
        f2bf(om1[0]), f2bf(om1[1]), f2bf(om1[2]), f2bf(om1[3]));
}

// ---------------------------------------------------------------------------
// proj: mean = (pmean[0]+pmean[1])/6 (bf16 partials) -> @ Wp (MFMA) -> + bp
// + skip. 256 blocks x 256 thr. Row index == pmean row index directly.
// p1 lives 4096 rows after p0 (FIX of R12's x64 offset bug).
// ---------------------------------------------------------------------------
__global__ __launch_bounds__(256)
void proj_kernel(const unsigned short* __restrict__ pmean,
                 const unsigned short* __restrict__ Wpt,
                 const float* __restrict__ bp,
                 const float* __restrict__ skip,
                 float* __restrict__ out)
{
    const int t    = threadIdx.x;
    const int wv   = t >> 6;        // out-quarter
    const int lane = t & 63;
    const int m16  = lane & 15;
    const int g    = lane >> 4;

    const int row  = blockIdx.x * 16 + m16;   // 0..4095 == pmean row

    short8 xf[4];
    #pragma unroll
    for (int kt = 0; kt < 4; ++kt) {
        const short8 p0 = *(const short8*)(
            pmean + (size_t)row * 128 + kt * 32 + g * 8);
        const short8 p1 = *(const short8*)(
            pmean + (size_t)4096 * 128 + (size_t)row * 128 + kt * 32 + g * 8);
        short8 pk;
        #pragma unroll
        for (int jj = 0; jj < 8; ++jj) {
            const float m = (bf2f((unsigned short)p0[jj]) +
                             bf2f((unsigned short)p1[jj])) * (1.0f / 6.0f);
            pk[jj] = (short)f2bf(m);
        }
        xf[kt] = pk;
    }

    f32x4 acc[2] = {{0,0,0,0},{0,0,0,0}};
    #pragma unroll
    for (int kt = 0; kt < 4; ++kt) {
        #pragma unroll
        for (int ot = 0; ot < 2; ++ot) {
            const short8 aw = *(const short8*)&Wpt[
                (size_t)((wv * 2 + ot) * 16 + m16) * 128 + kt * 32 + g * 8];
            acc[ot] = __builtin_amdgcn_mfma_f32_16x16x32_bf16(aw, xf[kt], acc[ot], 0, 0, 0);
        }
    }

    #pragma unroll
    for (int ot = 0; ot < 2; ++ot) {
        const int ob = (wv * 2 + ot) * 16 + g * 4;
        const float4 bb = *(const float4*)&bp[ob];
        const float4 sk = *(const float4*)&skip[(size_t)row * D + ob];
        float4 r;
        r.x = acc[ot][0] + bb.x + sk.x;
        r.y = acc[ot][1] + bb.y + sk.y;
        r.z = acc[ot][2] + bb.z + sk.z;
        r.w = acc[ot][3] + bb.w + sk.w;
        *(float4*)&out[(size_t)row * D + ob] = r;
    }
}

// ---------------------------------------------------------------------------
extern "C" void kernel_launch(void* const* d_in, const int* in_sizes, int n_in,
                              void* d_out, int out_size, void* d_ws, size_t ws_size,
                              hipStream_t stream)
{
    const float* q          = (const float*)d_in[0];
    const float* k          = (const float*)d_in[1];
    const float* v          = (const float*)d_in[2];
    const float* skip       = (const float*)d_in[3];
    const float* attn_scale = (const float*)d_in[4];
    const float* lnq_g      = (const float*)d_in[5];
    const float* lnq_b      = (const float*)d_in[6];
    const float* Wq         = (const float*)d_in[7];
    const float* bq         = (const float*)d_in[8];
    const float* lnk_g      = (const float*)d_in[9];
    const float* lnk_b      = (const float*)d_in[10];
    const float* Wk         = (const float*)d_in[11];
    const float* bk         = (const float*)d_in[12];
    const float* lnv_g      = (const float*)d_in[13];
    const float* lnv_b      = (const float*)d_in[14];
    const float* Wv         = (const float*)d_in[15];
    const float* bv         = (const float*)d_in[16];
    const float* Wp         = (const float*)d_in[17];
    const float* bp         = (const float*)d_in[18];

    float* out = (float*)d_out;
    char*  wsb = (char*)d_ws;

    // ws layout (bytes)
    unsigned short* qbuf  = (unsigned short*)(wsb);              //  6,291,456
    unsigned short* kbuf  = (unsigned short*)(wsb + 6291456);    //  7,864,320
    unsigned short* vtb   = (unsigned short*)(wsb + 14155776);   //  7,864,320
    unsigned short* Wt    = (unsigned short*)(wsb + 22020096);   //     98,304
    unsigned short* Wpt   = (unsigned short*)(wsb + 22118400);   //     32,768
    float*          c1    = (float*)        (wsb + 22151168);    //      1,536
    float*          c2    = (float*)        (wsb + 22152704);    //      1,536
    unsigned short* pmean = (unsigned short*)(wsb + 22154240);   //  2,097,152 (2x1MB)

    wprep_kernel<<<512, 64, 0, stream>>>(Wq, Wk, Wv, Wp,
                                         lnq_g, lnq_b, bq,
                                         lnk_g, lnk_b, bk,
                                         lnv_g, lnv_b, bv,
                                         (unsigned*)Wt, (unsigned*)Wpt, c1, c2);

    ln_fused_kernel<<<1344, 256, 0, stream>>>(q, k, v, Wt, c1, c2,
                                              qbuf, kbuf, vtb, attn_scale);

    dim3 agrid(64, 4, 2);
    attn_kernel<<<agrid, 256, 0, stream>>>(qbuf, kbuf, vtb, pmean);

    proj_kernel<<<256, 256, 0, stream>>>(pmean, Wpt, bp, skip, out);
}